// Round 1
// baseline (429.019 us; speedup 1.0000x reference)
//
#include <hip/hip_runtime.h>
#include <math.h>

// ---------------------------------------------------------------------------
// GCN critic network, fp32 throughout.
// Pipeline per launch:
//   memset(degc) -> hist -> dinv -> scanA/B/C (CSR row_ptr) -> fill (CSR)
//   -> [mm -> agg]×3 -> pool -> head
// CSR "pull" aggregation: one wave per node, 64 lanes = 64 features, no float
// atomics anywhere in the layer loop.
// ---------------------------------------------------------------------------

__global__ __launch_bounds__(256) void hist_kernel(const int* __restrict__ dst,
                                                   int* __restrict__ degc, int E) {
  int e = blockIdx.x * 256 + threadIdx.x;
  if (e < E) atomicAdd(&degc[dst[e]], 1);
}

__global__ __launch_bounds__(256) void dinv_kernel(const int* __restrict__ degc,
                                                   float* __restrict__ dinv, int n) {
  int i = blockIdx.x * 256 + threadIdx.x;
  if (i < n) dinv[i] = 1.0f / sqrtf((float)degc[i] + 1.0f);
}

// --- hierarchical exclusive scan of degc -> rowptr (and cursor copy) --------
__global__ __launch_bounds__(256) void scanA_kernel(const int* __restrict__ deg,
                                                    int* __restrict__ bsum, int n) {
  __shared__ int sdata[256];
  int t = threadIdx.x;
  int i = blockIdx.x * 256 + t;
  sdata[t] = (i < n) ? deg[i] : 0;
  __syncthreads();
  for (int off = 128; off > 0; off >>= 1) {
    if (t < off) sdata[t] += sdata[t + off];
    __syncthreads();
  }
  if (t == 0) bsum[blockIdx.x] = sdata[0];
}

__global__ __launch_bounds__(256) void scanB_kernel(int* __restrict__ bsum, int nb) {
  __shared__ int s[256];
  int t = threadIdx.x;
  int v = (t < nb) ? bsum[t] : 0;
  s[t] = v;
  __syncthreads();
  for (int off = 1; off < 256; off <<= 1) {
    int x = (t >= off) ? s[t - off] : 0;
    __syncthreads();
    s[t] += x;
    __syncthreads();
  }
  if (t < nb) bsum[t] = s[t] - v;  // exclusive block offsets
}

__global__ __launch_bounds__(256) void scanC_kernel(const int* __restrict__ deg,
                                                    const int* __restrict__ bsum,
                                                    int* __restrict__ rowptr,
                                                    int* __restrict__ cursor,
                                                    int n, int e_total) {
  __shared__ int s[256];
  int t = threadIdx.x;
  int i = blockIdx.x * 256 + t;
  int v = (i < n) ? deg[i] : 0;
  s[t] = v;
  __syncthreads();
  for (int off = 1; off < 256; off <<= 1) {
    int x = (t >= off) ? s[t - off] : 0;
    __syncthreads();
    s[t] += x;
    __syncthreads();
  }
  if (i < n) {
    int excl = bsum[blockIdx.x] + s[t] - v;
    rowptr[i] = excl;
    cursor[i] = excl;
  }
  if (i == 0) rowptr[n] = e_total;
}

__global__ __launch_bounds__(256) void fill_kernel(const int* __restrict__ src,
                                                   const int* __restrict__ dst,
                                                   const float* __restrict__ dinv,
                                                   int* __restrict__ cursor,
                                                   int* __restrict__ csr_src,
                                                   float* __restrict__ csr_coef, int E) {
  int e = blockIdx.x * 256 + threadIdx.x;
  if (e >= E) return;
  int s = src[e], d = dst[e];
  int pos = atomicAdd(&cursor[d], 1);
  csr_src[pos] = s;
  csr_coef[pos] = dinv[s] * dinv[d];
}

// --- dense matmul C[N,64] = A[N,K] @ W[K,64] --------------------------------
// One wave computes 16 rows x 64 cols. A-row addresses are wave-uniform
// (readfirstlane on the wave id) -> compiler emits s_load_dwordx4 for A; the
// W rows are 256B coalesced vector loads that stay L1-resident (W <= 32 KiB).
template <int K>
__global__ __launch_bounds__(256) void mm_kernel(const float* __restrict__ A,
                                                 const float* __restrict__ W,
                                                 float* __restrict__ C, int nrows) {
  const int lane = threadIdx.x & 63;
  const int wid = __builtin_amdgcn_readfirstlane(threadIdx.x >> 6);
  const int row0 = blockIdx.x * 64 + wid * 16;
  float acc[16];
#pragma unroll
  for (int r = 0; r < 16; ++r) acc[r] = 0.0f;
  const float* Arow = A + (size_t)row0 * K;
  const bool full = (row0 + 16 <= nrows);
  for (int k0 = 0; k0 < K; k0 += 4) {
    float w0 = W[(k0 + 0) * 64 + lane];
    float w1 = W[(k0 + 1) * 64 + lane];
    float w2 = W[(k0 + 2) * 64 + lane];
    float w3 = W[(k0 + 3) * 64 + lane];
    if (full) {
#pragma unroll
      for (int r = 0; r < 16; ++r) {
        float4 a = *(const float4*)(Arow + r * K + k0);  // uniform -> s_load
        acc[r] = fmaf(a.x, w0, acc[r]);
        acc[r] = fmaf(a.y, w1, acc[r]);
        acc[r] = fmaf(a.z, w2, acc[r]);
        acc[r] = fmaf(a.w, w3, acc[r]);
      }
    } else {
#pragma unroll
      for (int r = 0; r < 16; ++r) {
        if (row0 + r < nrows) {
          float4 a = *(const float4*)(Arow + r * K + k0);
          acc[r] = fmaf(a.x, w0, acc[r]);
          acc[r] = fmaf(a.y, w1, acc[r]);
          acc[r] = fmaf(a.z, w2, acc[r]);
          acc[r] = fmaf(a.w, w3, acc[r]);
        }
      }
    }
  }
#pragma unroll
  for (int r = 0; r < 16; ++r) {
    int row = row0 + r;
    if (row < nrows) C[(size_t)row * 64 + lane] = acc[r];
  }
}

// --- CSR pull aggregation + self loop + bias + relu -------------------------
__global__ __launch_bounds__(256) void agg_kernel(const float* __restrict__ h,
                                                  const int* __restrict__ rowptr,
                                                  const int* __restrict__ csr_src,
                                                  const float* __restrict__ csr_coef,
                                                  const float* __restrict__ dinv,
                                                  const float* __restrict__ bias,
                                                  float* __restrict__ out, int n) {
  const int lane = threadIdx.x & 63;
  const int wid = __builtin_amdgcn_readfirstlane(threadIdx.x >> 6);
  const int node = blockIdx.x * 4 + wid;
  if (node >= n) return;
  const float di = dinv[node];
  float acc = di * di * h[node * 64 + lane];
  const int beg = rowptr[node];
  const int end = rowptr[node + 1];
  int j = beg;
  for (; j + 2 <= end; j += 2) {
    int s0 = csr_src[j], s1 = csr_src[j + 1];
    float c0 = csr_coef[j], c1 = csr_coef[j + 1];
    float v0 = h[s0 * 64 + lane];
    float v1 = h[s1 * 64 + lane];
    acc = fmaf(c0, v0, acc);
    acc = fmaf(c1, v1, acc);
  }
  if (j < end) {
    int s0 = csr_src[j];
    acc = fmaf(csr_coef[j], h[s0 * 64 + lane], acc);
  }
  out[node * 64 + lane] = fmaxf(acc + bias[lane], 0.0f);
}

// --- pooling: per-feature sum and max over all nodes ------------------------
__global__ __launch_bounds__(256) void pool_kernel(const float* __restrict__ g,
                                                   float* __restrict__ psum,
                                                   unsigned int* __restrict__ pmax, int n) {
  __shared__ float ls[4][64];
  __shared__ float lm[4][64];
  int lane = threadIdx.x & 63;
  int wid = threadIdx.x >> 6;
  float s = 0.0f, m = 0.0f;  // values are post-relu (>=0), so 0 is identity for max
  for (int node = blockIdx.x * 4 + wid; node < n; node += gridDim.x * 4) {
    float v = g[node * 64 + lane];
    s += v;
    m = fmaxf(m, v);
  }
  ls[wid][lane] = s;
  lm[wid][lane] = m;
  __syncthreads();
  if (wid == 0) {
    for (int w = 1; w < 4; ++w) {
      s += ls[w][lane];
      m = fmaxf(m, lm[w][lane]);
    }
    atomicAdd(&psum[lane], s);
    atomicMax(&pmax[lane], __float_as_uint(m));  // valid: m >= 0
  }
}

// --- MLP head: [1,128] -> relu fc1 [128,64] -> fc2 [64,1] -------------------
__global__ __launch_bounds__(64) void head_kernel(const float* __restrict__ psum,
                                                  const float* __restrict__ pmaxf,
                                                  const float* __restrict__ fw1,
                                                  const float* __restrict__ fb1,
                                                  const float* __restrict__ fw2,
                                                  const float* __restrict__ fb2,
                                                  float* __restrict__ out, float invN) {
  int lane = threadIdx.x;
  float acc = fb1[lane];
#pragma unroll 4
  for (int k = 0; k < 64; ++k)
    acc = fmaf(psum[k] * invN, fw1[k * 64 + lane], acc);
#pragma unroll 4
  for (int k = 0; k < 64; ++k)
    acc = fmaf(pmaxf[k], fw1[(64 + k) * 64 + lane], acc);
  float a = fmaxf(acc, 0.0f) * fw2[lane];
  for (int off = 32; off > 0; off >>= 1) a += __shfl_down(a, off);
  if (lane == 0) out[0] = a + fb2[0];
}

extern "C" void kernel_launch(void* const* d_in, const int* in_sizes, int n_in,
                              void* d_out, int out_size, void* d_ws, size_t ws_size,
                              hipStream_t stream) {
  const float* x   = (const float*)d_in[0];
  const int*   ei  = (const int*)d_in[1];
  const float* W1  = (const float*)d_in[2];
  const float* b1  = (const float*)d_in[3];
  const float* W2  = (const float*)d_in[4];
  const float* b2  = (const float*)d_in[5];
  const float* W3  = (const float*)d_in[6];
  const float* b3  = (const float*)d_in[7];
  const float* fw1 = (const float*)d_in[8];
  const float* fb1 = (const float*)d_in[9];
  const float* fw2 = (const float*)d_in[10];
  const float* fb2 = (const float*)d_in[11];
  float* out = (float*)d_out;

  const int N = in_sizes[0] / 128;  // 50000
  const int E = in_sizes[1] / 2;    // 800000
  const int* src = ei;
  const int* dst = ei + E;

  // workspace carve-up (256B aligned slices)
  char* ws = (char*)d_ws;
  size_t off = 0;
  auto alloc = [&](size_t bytes) -> char* {
    char* p = ws + off;
    off = (off + bytes + 255) & ~(size_t)255;
    return p;
  };
  float*        dinv     = (float*)alloc((size_t)N * 4);
  int*          degc     = (int*)alloc((size_t)N * 4);
  int*          rowptr   = (int*)alloc((size_t)(N + 1) * 4);
  int*          cursor   = (int*)alloc((size_t)N * 4);
  int*          bsum     = (int*)alloc(256 * 4);
  int*          csr_src  = (int*)alloc((size_t)E * 4);
  float*        csr_coef = (float*)alloc((size_t)E * 4);
  float*        bufA     = (float*)alloc((size_t)N * 64 * 4);
  float*        bufB     = (float*)alloc((size_t)N * 64 * 4);
  float*        psum     = (float*)alloc(64 * 4);
  unsigned int* pmax     = (unsigned int*)alloc(64 * 4);

  const int histBlk = (E + 255) / 256;
  const int nodeBlk = (N + 255) / 256;
  const int scanBlk = (N + 255) / 256;  // 196 (<= 256, required by scanB)
  const int mmBlk   = (N + 63) / 64;
  const int aggBlk  = (N + 3) / 4;

  // ws is re-poisoned (0xAA) before every timed launch -> re-init everything
  hipMemsetAsync(degc, 0, (size_t)N * 4, stream);
  hipMemsetAsync(psum, 0, 64 * 4, stream);
  hipMemsetAsync(pmax, 0, 64 * 4, stream);

  hist_kernel<<<histBlk, 256, 0, stream>>>(dst, degc, E);
  dinv_kernel<<<nodeBlk, 256, 0, stream>>>(degc, dinv, N);
  scanA_kernel<<<scanBlk, 256, 0, stream>>>(degc, bsum, N);
  scanB_kernel<<<1, 256, 0, stream>>>(bsum, scanBlk);
  scanC_kernel<<<scanBlk, 256, 0, stream>>>(degc, bsum, rowptr, cursor, N, E);
  fill_kernel<<<histBlk, 256, 0, stream>>>(src, dst, dinv, cursor, csr_src, csr_coef, E);

  // layer 1: x[N,128] @ W1 -> bufA; aggregate -> bufB
  mm_kernel<128><<<mmBlk, 256, 0, stream>>>(x, W1, bufA, N);
  agg_kernel<<<aggBlk, 256, 0, stream>>>(bufA, rowptr, csr_src, csr_coef, dinv, b1, bufB, N);
  // layer 2
  mm_kernel<64><<<mmBlk, 256, 0, stream>>>(bufB, W2, bufA, N);
  agg_kernel<<<aggBlk, 256, 0, stream>>>(bufA, rowptr, csr_src, csr_coef, dinv, b2, bufB, N);
  // layer 3
  mm_kernel<64><<<mmBlk, 256, 0, stream>>>(bufB, W3, bufA, N);
  agg_kernel<<<aggBlk, 256, 0, stream>>>(bufA, rowptr, csr_src, csr_coef, dinv, b3, bufB, N);

  pool_kernel<<<256, 256, 0, stream>>>(bufB, psum, pmax, N);
  head_kernel<<<1, 64, 0, stream>>>(psum, (const float*)pmax, fw1, fb1, fw2, fb2, out,
                                    1.0f / (float)N);
}

// Round 2
// 370.715 us; speedup vs baseline: 1.1573x; 1.1573x over previous
//
#include <hip/hip_runtime.h>
#include <math.h>

// ---------------------------------------------------------------------------
// GCN critic network, fp32 throughout.
// Pipeline per launch:
//   memset(degc) -> hist -> dinv -> scanA/B/C (CSR row_ptr) -> fill (CSR)
//   -> [mm -> agg]×3 -> pool -> head
// mm v2: lane=row, A-tile in LDS (XOR-swizzled column reads, conflict-free),
// W via wave-uniform scalar loads (tiny, cache-resident). 1 ds_read_b32 +
// 16 FMA per k per wave -> VALU-bound instead of scalar-load-latency-bound.
// ---------------------------------------------------------------------------

__global__ __launch_bounds__(256) void hist_kernel(const int* __restrict__ dst,
                                                   int* __restrict__ degc, int E) {
  int e = blockIdx.x * 256 + threadIdx.x;
  if (e < E) atomicAdd(&degc[dst[e]], 1);
}

__global__ __launch_bounds__(256) void dinv_kernel(const int* __restrict__ degc,
                                                   float* __restrict__ dinv, int n) {
  int i = blockIdx.x * 256 + threadIdx.x;
  if (i < n) dinv[i] = 1.0f / sqrtf((float)degc[i] + 1.0f);
}

// --- hierarchical exclusive scan of degc -> rowptr (and cursor copy) --------
__global__ __launch_bounds__(256) void scanA_kernel(const int* __restrict__ deg,
                                                    int* __restrict__ bsum, int n) {
  __shared__ int sdata[256];
  int t = threadIdx.x;
  int i = blockIdx.x * 256 + t;
  sdata[t] = (i < n) ? deg[i] : 0;
  __syncthreads();
  for (int off = 128; off > 0; off >>= 1) {
    if (t < off) sdata[t] += sdata[t + off];
    __syncthreads();
  }
  if (t == 0) bsum[blockIdx.x] = sdata[0];
}

__global__ __launch_bounds__(256) void scanB_kernel(int* __restrict__ bsum, int nb) {
  __shared__ int s[256];
  int t = threadIdx.x;
  int v = (t < nb) ? bsum[t] : 0;
  s[t] = v;
  __syncthreads();
  for (int off = 1; off < 256; off <<= 1) {
    int x = (t >= off) ? s[t - off] : 0;
    __syncthreads();
    s[t] += x;
    __syncthreads();
  }
  if (t < nb) bsum[t] = s[t] - v;  // exclusive block offsets
}

__global__ __launch_bounds__(256) void scanC_kernel(const int* __restrict__ deg,
                                                    const int* __restrict__ bsum,
                                                    int* __restrict__ rowptr,
                                                    int* __restrict__ cursor,
                                                    int n, int e_total) {
  __shared__ int s[256];
  int t = threadIdx.x;
  int i = blockIdx.x * 256 + t;
  int v = (i < n) ? deg[i] : 0;
  s[t] = v;
  __syncthreads();
  for (int off = 1; off < 256; off <<= 1) {
    int x = (t >= off) ? s[t - off] : 0;
    __syncthreads();
    s[t] += x;
    __syncthreads();
  }
  if (i < n) {
    int excl = bsum[blockIdx.x] + s[t] - v;
    rowptr[i] = excl;
    cursor[i] = excl;
  }
  if (i == 0) rowptr[n] = e_total;
}

__global__ __launch_bounds__(256) void fill_kernel(const int* __restrict__ src,
                                                   const int* __restrict__ dst,
                                                   const float* __restrict__ dinv,
                                                   int* __restrict__ cursor,
                                                   int* __restrict__ csr_src,
                                                   float* __restrict__ csr_coef, int E) {
  int e = blockIdx.x * 256 + threadIdx.x;
  if (e >= E) return;
  int s = src[e], d = dst[e];
  int pos = atomicAdd(&cursor[d], 1);
  csr_src[pos] = s;
  csr_coef[pos] = dinv[s] * dinv[d];
}

// --- dense matmul C[N,64] = A[N,K] @ W[K,64], v2 ----------------------------
// Block: 256 threads, 64 rows. lane = row within tile; wave w owns cols
// [16w, 16w+16). A-tile staged once into LDS, swizzled As[r*K + (k ^ (r&31))]
// so the column read (all 64 lanes, same k, different r) hits 32 distinct
// banks (2 lanes/bank = free). W reads are wave-uniform -> s_load, and W is
// <=32 KiB shared by every block -> scalar-cache/L2 resident. Inner loop per
// k: 1 ds_read_b32 + 16 v_fmac (SGPR W operand). No barriers after staging.
template <int K>
__global__ __launch_bounds__(256) void mm_kernel(const float* __restrict__ A,
                                                 const float* __restrict__ W,
                                                 float* __restrict__ C, int nrows) {
  __shared__ float As[64 * K];
  const int t = threadIdx.x;
  const int lane = t & 63;
  const int wid = __builtin_amdgcn_readfirstlane(t >> 6);
  const int row0 = blockIdx.x * 64;

  // ---- stage A tile (64 rows x K floats) into LDS, swizzled ----
  constexpr int F4_PER_ROW = K / 4;
  constexpr int ROW_SHIFT = (K == 128) ? 5 : 4;  // log2(F4_PER_ROW)
#pragma unroll
  for (int i = 0; i < K / 16; ++i) {  // 256 threads x K/16 float4 = 64*K floats
    int e4 = t + 256 * i;
    int r = e4 >> ROW_SHIFT;
    int k = (e4 & (F4_PER_ROW - 1)) * 4;
    int rc = row0 + r;
    if (rc > nrows - 1) rc = nrows - 1;  // clamp: garbage rows never stored
    float4 v = *(const float4*)(A + (size_t)rc * K + k);
    int s = r & 31;
    As[r * K + ((k + 0) ^ s)] = v.x;
    As[r * K + ((k + 1) ^ s)] = v.y;
    As[r * K + ((k + 2) ^ s)] = v.z;
    As[r * K + ((k + 3) ^ s)] = v.w;
  }
  __syncthreads();

  const int colbase = wid * 16;
  const float* Wc = W + colbase;
  float acc[16];
#pragma unroll
  for (int j = 0; j < 16; ++j) acc[j] = 0.0f;
  const int sw = lane & 31;
  const float* Arow = As + lane * K;

#pragma unroll 4
  for (int k = 0; k < K; ++k) {
    float a = Arow[k ^ sw];            // ds_read_b32, conflict-free
    const float* Wk = Wc + k * 64;     // wave-uniform -> s_load
#pragma unroll
    for (int j = 0; j < 16; ++j) acc[j] = fmaf(a, Wk[j], acc[j]);
  }

  int row = row0 + lane;
  if (row < nrows) {
    float* Crow = C + (size_t)row * 64 + colbase;
#pragma unroll
    for (int q = 0; q < 4; ++q) {
      float4 v = make_float4(acc[4 * q + 0], acc[4 * q + 1], acc[4 * q + 2], acc[4 * q + 3]);
      *(float4*)(Crow + 4 * q) = v;
    }
  }
}

// --- CSR pull aggregation + self loop + bias + relu -------------------------
__global__ __launch_bounds__(256) void agg_kernel(const float* __restrict__ h,
                                                  const int* __restrict__ rowptr,
                                                  const int* __restrict__ csr_src,
                                                  const float* __restrict__ csr_coef,
                                                  const float* __restrict__ dinv,
                                                  const float* __restrict__ bias,
                                                  float* __restrict__ out, int n) {
  const int lane = threadIdx.x & 63;
  const int wid = __builtin_amdgcn_readfirstlane(threadIdx.x >> 6);
  const int node = blockIdx.x * 4 + wid;
  if (node >= n) return;
  const float di = dinv[node];
  float acc = di * di * h[node * 64 + lane];
  const int beg = rowptr[node];
  const int end = rowptr[node + 1];
  int j = beg;
  for (; j + 4 <= end; j += 4) {
    int s0 = csr_src[j], s1 = csr_src[j + 1], s2 = csr_src[j + 2], s3 = csr_src[j + 3];
    float c0 = csr_coef[j], c1 = csr_coef[j + 1], c2 = csr_coef[j + 2], c3 = csr_coef[j + 3];
    float v0 = h[s0 * 64 + lane];
    float v1 = h[s1 * 64 + lane];
    float v2 = h[s2 * 64 + lane];
    float v3 = h[s3 * 64 + lane];
    acc = fmaf(c0, v0, acc);
    acc = fmaf(c1, v1, acc);
    acc = fmaf(c2, v2, acc);
    acc = fmaf(c3, v3, acc);
  }
  for (; j < end; ++j) {
    int s0 = csr_src[j];
    acc = fmaf(csr_coef[j], h[s0 * 64 + lane], acc);
  }
  out[node * 64 + lane] = fmaxf(acc + bias[lane], 0.0f);
}

// --- pooling: per-feature sum and max over all nodes ------------------------
__global__ __launch_bounds__(256) void pool_kernel(const float* __restrict__ g,
                                                   float* __restrict__ psum,
                                                   unsigned int* __restrict__ pmax, int n) {
  __shared__ float ls[4][64];
  __shared__ float lm[4][64];
  int lane = threadIdx.x & 63;
  int wid = threadIdx.x >> 6;
  float s = 0.0f, m = 0.0f;  // values are post-relu (>=0), so 0 is identity for max
  for (int node = blockIdx.x * 4 + wid; node < n; node += gridDim.x * 4) {
    float v = g[node * 64 + lane];
    s += v;
    m = fmaxf(m, v);
  }
  ls[wid][lane] = s;
  lm[wid][lane] = m;
  __syncthreads();
  if (wid == 0) {
    for (int w = 1; w < 4; ++w) {
      s += ls[w][lane];
      m = fmaxf(m, lm[w][lane]);
    }
    atomicAdd(&psum[lane], s);
    atomicMax(&pmax[lane], __float_as_uint(m));  // valid: m >= 0
  }
}

// --- MLP head: [1,128] -> relu fc1 [128,64] -> fc2 [64,1] -------------------
__global__ __launch_bounds__(64) void head_kernel(const float* __restrict__ psum,
                                                  const float* __restrict__ pmaxf,
                                                  const float* __restrict__ fw1,
                                                  const float* __restrict__ fb1,
                                                  const float* __restrict__ fw2,
                                                  const float* __restrict__ fb2,
                                                  float* __restrict__ out, float invN) {
  int lane = threadIdx.x;
  float acc = fb1[lane];
#pragma unroll 4
  for (int k = 0; k < 64; ++k)
    acc = fmaf(psum[k] * invN, fw1[k * 64 + lane], acc);
#pragma unroll 4
  for (int k = 0; k < 64; ++k)
    acc = fmaf(pmaxf[k], fw1[(64 + k) * 64 + lane], acc);
  float a = fmaxf(acc, 0.0f) * fw2[lane];
  for (int off = 32; off > 0; off >>= 1) a += __shfl_down(a, off);
  if (lane == 0) out[0] = a + fb2[0];
}

extern "C" void kernel_launch(void* const* d_in, const int* in_sizes, int n_in,
                              void* d_out, int out_size, void* d_ws, size_t ws_size,
                              hipStream_t stream) {
  const float* x   = (const float*)d_in[0];
  const int*   ei  = (const int*)d_in[1];
  const float* W1  = (const float*)d_in[2];
  const float* b1  = (const float*)d_in[3];
  const float* W2  = (const float*)d_in[4];
  const float* b2  = (const float*)d_in[5];
  const float* W3  = (const float*)d_in[6];
  const float* b3  = (const float*)d_in[7];
  const float* fw1 = (const float*)d_in[8];
  const float* fb1 = (const float*)d_in[9];
  const float* fw2 = (const float*)d_in[10];
  const float* fb2 = (const float*)d_in[11];
  float* out = (float*)d_out;

  const int N = in_sizes[0] / 128;  // 50000
  const int E = in_sizes[1] / 2;    // 800000
  const int* src = ei;
  const int* dst = ei + E;

  // workspace carve-up (256B aligned slices)
  char* ws = (char*)d_ws;
  size_t off = 0;
  auto alloc = [&](size_t bytes) -> char* {
    char* p = ws + off;
    off = (off + bytes + 255) & ~(size_t)255;
    return p;
  };
  float*        dinv     = (float*)alloc((size_t)N * 4);
  int*          degc     = (int*)alloc((size_t)N * 4);
  int*          rowptr   = (int*)alloc((size_t)(N + 1) * 4);
  int*          cursor   = (int*)alloc((size_t)N * 4);
  int*          bsum     = (int*)alloc(256 * 4);
  int*          csr_src  = (int*)alloc((size_t)E * 4);
  float*        csr_coef = (float*)alloc((size_t)E * 4);
  float*        bufA     = (float*)alloc((size_t)N * 64 * 4);
  float*        bufB     = (float*)alloc((size_t)N * 64 * 4);
  float*        psum     = (float*)alloc(64 * 4);
  unsigned int* pmax     = (unsigned int*)alloc(64 * 4);

  const int histBlk = (E + 255) / 256;
  const int nodeBlk = (N + 255) / 256;
  const int scanBlk = (N + 255) / 256;  // 196 (<= 256, required by scanB)
  const int mmBlk   = (N + 63) / 64;
  const int aggBlk  = (N + 3) / 4;

  // ws is re-poisoned (0xAA) before every timed launch -> re-init everything
  hipMemsetAsync(degc, 0, (size_t)N * 4, stream);
  hipMemsetAsync(psum, 0, 64 * 4, stream);
  hipMemsetAsync(pmax, 0, 64 * 4, stream);

  hist_kernel<<<histBlk, 256, 0, stream>>>(dst, degc, E);
  dinv_kernel<<<nodeBlk, 256, 0, stream>>>(degc, dinv, N);
  scanA_kernel<<<scanBlk, 256, 0, stream>>>(degc, bsum, N);
  scanB_kernel<<<1, 256, 0, stream>>>(bsum, scanBlk);
  scanC_kernel<<<scanBlk, 256, 0, stream>>>(degc, bsum, rowptr, cursor, N, E);
  fill_kernel<<<histBlk, 256, 0, stream>>>(src, dst, dinv, cursor, csr_src, csr_coef, E);

  // layer 1: x[N,128] @ W1 -> bufA; aggregate -> bufB
  mm_kernel<128><<<mmBlk, 256, 0, stream>>>(x, W1, bufA, N);
  agg_kernel<<<aggBlk, 256, 0, stream>>>(bufA, rowptr, csr_src, csr_coef, dinv, b1, bufB, N);
  // layer 2
  mm_kernel<64><<<mmBlk, 256, 0, stream>>>(bufB, W2, bufA, N);
  agg_kernel<<<aggBlk, 256, 0, stream>>>(bufA, rowptr, csr_src, csr_coef, dinv, b2, bufB, N);
  // layer 3
  mm_kernel<64><<<mmBlk, 256, 0, stream>>>(bufB, W3, bufA, N);
  agg_kernel<<<aggBlk, 256, 0, stream>>>(bufA, rowptr, csr_src, csr_coef, dinv, b3, bufB, N);

  pool_kernel<<<256, 256, 0, stream>>>(bufB, psum, pmax, N);
  head_kernel<<<1, 64, 0, stream>>>(psum, (const float*)pmax, fw1, fb1, fw2, fb2, out,
                                    1.0f / (float)N);
}